// Round 16
// baseline (122.863 us; speedup 1.0000x reference)
//
#include <hip/hip_runtime.h>

#define Hc     512
#define Wc     512
#define OH     506
#define OW     506
#define NPIX   (Hc * Wc)
#define BATCH  64
#define CHUNKS 16

#define BH     16                          // output rows per band
#define NBAND  32                          // 31*16=496, band 31 covers 496-505
#define NW     3                           // col-chunks (strips) per image row
#define WPB    4                           // waves (bands) per block
#define BLK_PER_STRIP (NBAND / WPB)        // 8
#define NSTRIP (BATCH * NW)                // 192
#define NBLK   (NSTRIP * BLK_PER_STRIP)    // 1536  (%8==0 -> bijective swizzle)
#define STRIPS_PER_XCD (NSTRIP / 8)        // 24
#define NPART  NBLK

typedef float f32x2 __attribute__((ext_vector_type(2)));
typedef float f32x4 __attribute__((ext_vector_type(4)));

// ---------------- Kernel 1: per-(sample,chunk) min/max partials -------------
__global__ __launch_bounds__(256) void mm_part_kernel(
    const float* __restrict__ X, const float* __restrict__ Y,
    float* __restrict__ part)
{
    int blk = blockIdx.x;            // 0 .. BATCH*CHUNKS-1
    int b   = blk >> 4;
    int ch  = blk & 15;
    size_t base = (size_t)b * NPIX + (size_t)ch * (NPIX / CHUNKS);
    const float4* x4 = (const float4*)(X + base);
    const float4* y4 = (const float4*)(Y + base);
    const int n4 = (NPIX / CHUNKS) / 4;   // 4096

    float mn = 1e38f, mx = -1e38f;
    for (int i = threadIdx.x; i < n4; i += 256) {
        float4 a = x4[i];
        float4 c = y4[i];
        mn = fminf(mn, fminf(fminf(a.x, a.y), fminf(a.z, a.w)));
        mx = fmaxf(mx, fmaxf(fmaxf(a.x, a.y), fmaxf(a.z, a.w)));
        mn = fminf(mn, fminf(fminf(c.x, c.y), fminf(c.z, c.w)));
        mx = fmaxf(mx, fmaxf(fmaxf(c.x, c.y), fmaxf(c.z, c.w)));
    }
    #pragma unroll
    for (int off = 1; off < 64; off <<= 1) {
        mn = fminf(mn, __shfl_xor(mn, off, 64));
        mx = fmaxf(mx, __shfl_xor(mx, off, 64));
    }
    __shared__ float smn[4], smx[4];
    int lane = threadIdx.x & 63, wid = threadIdx.x >> 6;
    if (lane == 0) { smn[wid] = mn; smx[wid] = mx; }
    __syncthreads();
    if (threadIdx.x == 0) {
        mn = fminf(fminf(smn[0], smn[1]), fminf(smn[2], smn[3]));
        mx = fmaxf(fmaxf(smx[0], smx[1]), fmaxf(smx[2], smx[3]));
        part[2 * blk]     = mn;
        part[2 * blk + 1] = mx;
    }
}

// ---------------- Kernel 2: streaming SSIM with packed LDS exchange ---------
// R13 structure/math (verified). Horizontal 7-window neighbor values now move
// via 4x ds_write_b128 + 4x ds_read_b128 (stats packed per-f32x4) instead of
// 16 ds_bpermute shuffles. Wave-private LDS slice: no __syncthreads.
__global__ __launch_bounds__(256, 8) void ssim_stream_kernel(
    const float* __restrict__ X, const float* __restrict__ Y,
    const float* __restrict__ mmpart, float* __restrict__ part)
{
    const int lane = threadIdx.x & 63;
    const int wid  = threadIdx.x >> 6;

    // per-wave exchange buffers: [stat-packed f32x4] per lane (+2 halo lanes)
    __shared__ float exA3[WPB][66][4];
    __shared__ float exA4[WPB][66][4];
    __shared__ float exV0[WPB][66][4];
    __shared__ float exT0[WPB][66][4];

    // zero the 2 halo lane slots (consumed only by masked outputs; must be
    // finite so 0*NaN can't poison the accumulator)
    if (lane < 2) {
        #pragma unroll
        for (int s = 0; s < 4; ++s) {
            exA3[wid][64 + lane][s] = 0.f;
            exA4[wid][64 + lane][s] = 0.f;
            exV0[wid][64 + lane][s] = 0.f;
            exT0[wid][64 + lane][s] = 0.f;
        }
    }

    // XCD-affine swizzle (bijective: NBLK % 8 == 0)
    const int lin   = blockIdx.x;            // 0..1535
    const int xcd   = lin & 7;
    const int slot  = lin >> 3;              // 0..191
    const int strip_local = slot >> 3;       // 0..23
    const int blk   = slot & 7;              // band-block within strip
    const int strip = xcd * STRIPS_PER_XCD + strip_local;   // 0..191
    const int img   = strip / NW;
    const int chunk = strip - img * NW;      // 0..2
    const int band  = blk * WPB + wid;       // 0..31

    // fold chunk min/max -> C1, C2 (uniform; L2-hot)
    float mn = 1e38f, mx = -1e38f;
    #pragma unroll
    for (int ch = 0; ch < CHUNKS; ++ch) {
        mn = fminf(mn, mmpart[2 * (img * CHUNKS + ch)]);
        mx = fmaxf(mx, mmpart[2 * (img * CHUNKS + ch) + 1]);
    }
    const float dr  = mx - mn;
    const float C1p = 2401.0f * (0.01f * dr) * (0.01f * dr);
    const float C2p = 2401.0f * (0.03f * dr) * (0.03f * dr);
    const f32x2 C1v = {C1p, C1p};
    const f32x2 C2v = {C2p, C2p};
    const f32x2 k49   = {49.0f, 49.0f};
    const f32x2 covn1 = {49.0f / 48.0f, 49.0f / 48.0f};
    const f32x2 covn2 = {2.0f * 49.0f / 48.0f, 2.0f * 49.0f / 48.0f};

    // chunk geometry
    const int cbase  = (chunk == 0) ? 0 : (chunk == 1) ? 248 : 496;
    const int out_lo = (chunk == 0) ? 0 : (chunk == 1) ? 250 : 498;
    const int out_hi = (chunk == 0) ? 249 : (chunk == 1) ? 497 : 505;

    const int col0  = cbase + 4 * lane;             // logical first col
    const int col0c = (col0 < 508) ? col0 : 508;    // clamped, 16B aligned
    f32x2 vm01, vm23;
    {
        float v[4];
        #pragma unroll
        for (int j = 0; j < 4; ++j) {
            int oc = col0 + j;
            v[j] = (oc >= out_lo && oc <= out_hi) ? 1.0f : 0.0f;
        }
        vm01 = (f32x2){v[0], v[1]};
        vm23 = (f32x2){v[2], v[3]};
    }

    const int oy0 = band * BH;
    const int nvalid = (OH - oy0) < BH ? (OH - oy0) : BH;   // 16, or 10 (band 31)

    const float* px = X + (size_t)img * NPIX + col0c;
    const float* py = Y + (size_t)img * NPIX + col0c;

    // packed running vertical sums: [0]=cols 0,1  [1]=cols 2,3
    f32x2 Vx[2]  = {{0,0},{0,0}}, Vy[2]  = {{0,0},{0,0}};
    f32x2 Vxy[2] = {{0,0},{0,0}}, Vss[2] = {{0,0},{0,0}};

    #define VADD(xa, ya)                                                     \
    {                                                                        \
        f32x2 xl = (xa).lo, xh = (xa).hi, yl = (ya).lo, yh = (ya).hi;        \
        Vx[0] += xl; Vx[1] += xh; Vy[0] += yl; Vy[1] += yh;                  \
        Vxy[0] += xl * yl; Vxy[1] += xh * yh;                                \
        Vss[0] += xl * xl + yl * yl; Vss[1] += xh * xh + yh * yh;            \
    }
    #define VSUB(xa, ya)                                                     \
    {                                                                        \
        f32x2 xl = (xa).lo, xh = (xa).hi, yl = (ya).lo, yh = (ya).hi;        \
        Vx[0] -= xl; Vx[1] -= xh; Vy[0] -= yl; Vy[1] -= yh;                  \
        Vxy[0] -= xl * yl; Vxy[1] -= xh * yh;                                \
        Vss[0] -= xl * xl + yl * yl; Vss[1] -= xh * xh + yh * yh;            \
    }

    // prologue: accumulate rows oy0..oy0+5 (max 501, no clamp)
    #pragma unroll
    for (int k = 0; k < 6; ++k) {
        f32x4 xa = *(const f32x4*)(px + (size_t)(oy0 + k) * Wc);
        f32x4 ya = *(const f32x4*)(py + (size_t)(oy0 + k) * Wc);
        VADD(xa, ya)
    }

    f32x2 acc2 = {0.f, 0.f};

    // per-stat prefix pieces: v1, v3, t01, u23, P3, P4
    #define PREP(V, V1o, V3o, T01o, U23o, P3o, P4o)                          \
        float V1o = V[0].y, V3o = V[1].y;                                    \
        float T01o = V[0].x + V[0].y, U23o = V[1].x + V[1].y;                \
        float P3o = T01o + V[1].x, P4o = T01o + U23o;

    // 49^2-prescaled SSIM for a packed pair of columns
    #define SSIM2(wx, wy, wp, ws, vmv)                                       \
    {                                                                        \
        f32x2 t1  = wx * wy;                                                 \
        f32x2 sq  = wx * wx + wy * wy;                                       \
        f32x2 F1  = t1 + t1 + C1v;                                           \
        f32x2 d1  = k49 * wp - t1;                                           \
        f32x2 F2  = covn2 * d1 + C2v;                                        \
        f32x2 F3  = sq + C1v;                                                \
        f32x2 d2  = k49 * ws - sq;                                           \
        f32x2 F4  = covn1 * d2 + C2v;                                        \
        f32x2 den = F3 * F4;                                                 \
        f32x2 num = F1 * F2;                                                 \
        f32x2 rv  = {__builtin_amdgcn_rcpf(den.x),                           \
                     __builtin_amdgcn_rcpf(den.y)};                          \
        acc2 += num * rv * vmv;                                              \
    }

    // running row pointers
    const float* pxi = px + (size_t)(oy0 + 6) * Wc;
    const float* pyi = py + (size_t)(oy0 + 6) * Wc;
    const float* pxo = px + (size_t)oy0 * Wc;
    const float* pyo = py + (size_t)oy0 * Wc;

    volatile f32x4* wrA3 = (volatile f32x4*)&exA3[wid][lane][0];
    volatile f32x4* wrA4 = (volatile f32x4*)&exA4[wid][lane][0];
    volatile f32x4* wrV0 = (volatile f32x4*)&exV0[wid][lane][0];
    volatile f32x4* wrT0 = (volatile f32x4*)&exT0[wid][lane][0];
    volatile const f32x4* rdA3 = (volatile const f32x4*)&exA3[wid][lane + 1][0];
    volatile const f32x4* rdA4 = (volatile const f32x4*)&exA4[wid][lane + 1][0];
    volatile const f32x4* rdV0 = (volatile const f32x4*)&exV0[wid][lane + 2][0];
    volatile const f32x4* rdT0 = (volatile const f32x4*)&exT0[wid][lane + 2][0];

    #pragma unroll 4
    for (int tt = 0; tt < nvalid; ++tt) {
        f32x4 xi = *(const f32x4*)pxi; pxi += Wc;
        f32x4 yi = *(const f32x4*)pyi; pyi += Wc;
        VADD(xi, yi)

        PREP(Vx,  vx1, vx3, tx, ux_, p3x, p4x)
        PREP(Vy,  vy1, vy3, ty, uy_, p3y, p4y)
        PREP(Vxy, vp1, vp3, tp, up_, p3p, p4p)
        PREP(Vss, vs1, vs3, ts, us_, p3s, p4s)

        // publish packed-across-stats (4x ds_write_b128, stride-16B: no conflicts)
        *wrA3 = (f32x4){p3x, p3y, p3p, p3s};
        *wrA4 = (f32x4){p4x, p4y, p4p, p4s};
        *wrV0 = (f32x4){Vx[0].x, Vy[0].x, Vxy[0].x, Vss[0].x};
        *wrT0 = (f32x4){tx, ty, tp, ts};
        asm volatile("s_waitcnt lgkmcnt(0)" :: );

        // neighbor reads (4x ds_read_b128)
        f32x4 rA3 = *rdA3;      // lane+1: P3 per stat
        f32x4 rA4 = *rdA4;      // lane+1: P4 per stat
        f32x4 rV0 = *rdV0;      // lane+2: v0 per stat
        f32x4 rT0 = *rdT0;      // lane+2: t01 per stat

        // W0 = P4 + A3; cc = u23 + A4; W1 = cc + v1; W2 = cc + B1; W3 = (v3+A4)+B2
        float ccx = ux_ + rA4.x, ccy = uy_ + rA4.y;
        float ccp = up_ + rA4.z, ccs = us_ + rA4.w;
        f32x2 wx01 = {p4x + rA3.x, ccx + vx1};
        f32x2 wx23 = {ccx + rV0.x, (vx3 + rA4.x) + rT0.x};
        f32x2 wy01 = {p4y + rA3.y, ccy + vy1};
        f32x2 wy23 = {ccy + rV0.y, (vy3 + rA4.y) + rT0.y};
        f32x2 wp01 = {p4p + rA3.z, ccp + vp1};
        f32x2 wp23 = {ccp + rV0.z, (vp3 + rA4.z) + rT0.z};
        f32x2 ws01 = {p4s + rA3.w, ccs + vs1};
        f32x2 ws23 = {ccs + rV0.w, (vs3 + rA4.w) + rT0.w};

        SSIM2(wx01, wy01, wp01, ws01, vm01)
        SSIM2(wx23, wy23, wp23, ws23, vm23)

        f32x4 xo = *(const f32x4*)pxo; pxo += Wc;
        f32x4 yo = *(const f32x4*)pyo; pyo += Wc;
        VSUB(xo, yo)
    }

    #undef SSIM2
    #undef PREP
    #undef VADD
    #undef VSUB

    float acc = acc2.x + acc2.y;
    // deterministic wave reduce + cross-wave LDS fold (one partial per block)
    #pragma unroll
    for (int off = 1; off < 64; off <<= 1)
        acc += __shfl_xor(acc, off, 64);
    __shared__ float sacc[4];
    if (lane == 0) sacc[wid] = acc;
    __syncthreads();
    if (threadIdx.x == 0)
        part[lin] = (sacc[0] + sacc[1]) + (sacc[2] + sacc[3]);
}

// ---------------- Kernel 3: final deterministic f64 reduction ---------------
__global__ __launch_bounds__(1024) void final_reduce_kernel(
    const float* __restrict__ part, float* __restrict__ out)
{
    __shared__ double sd[1024];
    double s = 0.0;
    for (int i = threadIdx.x; i < NPART; i += 1024)
        s += (double)part[i];
    sd[threadIdx.x] = s;
    __syncthreads();
    for (int off = 512; off > 0; off >>= 1) {
        if (threadIdx.x < off) sd[threadIdx.x] += sd[threadIdx.x + off];
        __syncthreads();
    }
    if (threadIdx.x == 0)
        out[0] = (float)(sd[0] / ((double)BATCH * OH * OW));
}

extern "C" void kernel_launch(void* const* d_in, const int* in_sizes, int n_in,
                              void* d_out, int out_size, void* d_ws, size_t ws_size,
                              hipStream_t stream) {
    const float* X = (const float*)d_in[0];
    const float* Y = (const float*)d_in[1];
    float* out = (float*)d_out;
    float* ws  = (float*)d_ws;

    float* mmpart = ws;                   // 2 * BATCH * CHUNKS = 2048 floats
    float* part   = ws + 2048;            // NPART = 1536 floats

    mm_part_kernel<<<BATCH * CHUNKS, 256, 0, stream>>>(X, Y, mmpart);
    ssim_stream_kernel<<<NBLK, 64 * WPB, 0, stream>>>(X, Y, mmpart, part);
    final_reduce_kernel<<<1, 1024, 0, stream>>>(part, out);
}

// Round 17
// 121.231 us; speedup vs baseline: 1.0135x; 1.0135x over previous
//
#include <hip/hip_runtime.h>

#define Hc     512
#define Wc     512
#define OH     506
#define OW     506
#define NPIX   (Hc * Wc)
#define BATCH  64
#define CHUNKS 16

#define BH     16                          // output rows per band
#define NBAND  32                          // 31*16=496, band 31 covers 496-505
#define NW     3                           // col-chunks (strips) per image row
#define WPB    4                           // waves (bands) per block
#define BLK_PER_STRIP (NBAND / WPB)        // 8
#define NSTRIP (BATCH * NW)                // 192
#define NBLK   (NSTRIP * BLK_PER_STRIP)    // 1536  (%8==0 -> bijective swizzle)
#define STRIPS_PER_XCD (NSTRIP / 8)        // 24
#define NPART  NBLK

typedef float f32x2 __attribute__((ext_vector_type(2)));
typedef float f32x4 __attribute__((ext_vector_type(4)));

// ---------------- Kernel 1: per-(sample,chunk) min/max partials -------------
// Block 0 also re-zeroes the ssim completion counter (graph-replay safe).
__global__ __launch_bounds__(256) void mm_part_kernel(
    const float* __restrict__ X, const float* __restrict__ Y,
    float* __restrict__ part, unsigned int* __restrict__ counter)
{
    if (blockIdx.x == 0 && threadIdx.x == 0) counter[0] = 0u;

    int blk = blockIdx.x;            // 0 .. BATCH*CHUNKS-1
    int b   = blk >> 4;
    int ch  = blk & 15;
    size_t base = (size_t)b * NPIX + (size_t)ch * (NPIX / CHUNKS);
    const float4* x4 = (const float4*)(X + base);
    const float4* y4 = (const float4*)(Y + base);
    const int n4 = (NPIX / CHUNKS) / 4;   // 4096

    float mn = 1e38f, mx = -1e38f;
    for (int i = threadIdx.x; i < n4; i += 256) {
        float4 a = x4[i];
        float4 c = y4[i];
        mn = fminf(mn, fminf(fminf(a.x, a.y), fminf(a.z, a.w)));
        mx = fmaxf(mx, fmaxf(fmaxf(a.x, a.y), fmaxf(a.z, a.w)));
        mn = fminf(mn, fminf(fminf(c.x, c.y), fminf(c.z, c.w)));
        mx = fmaxf(mx, fmaxf(fmaxf(c.x, c.y), fmaxf(c.z, c.w)));
    }
    #pragma unroll
    for (int off = 1; off < 64; off <<= 1) {
        mn = fminf(mn, __shfl_xor(mn, off, 64));
        mx = fmaxf(mx, __shfl_xor(mx, off, 64));
    }
    __shared__ float smn[4], smx[4];
    int lane = threadIdx.x & 63, wid = threadIdx.x >> 6;
    if (lane == 0) { smn[wid] = mn; smx[wid] = mx; }
    __syncthreads();
    if (threadIdx.x == 0) {
        mn = fminf(fminf(smn[0], smn[1]), fminf(smn[2], smn[3]));
        mx = fmaxf(fmaxf(smx[0], smx[1]), fmaxf(smx[2], smx[3]));
        part[2 * blk]     = mn;
        part[2 * blk + 1] = mx;
    }
}

// ---------------- Kernel 2: streaming SSIM + fused final reduction ----------
// R13 body (verified champion). After the block partial is written, the
// last-arriving block performs the deterministic f64 reduction (single block,
// fixed order) -- eliminates the third kernel launch.
__global__ __launch_bounds__(256, 8) void ssim_stream_kernel(
    const float* __restrict__ X, const float* __restrict__ Y,
    const float* __restrict__ mmpart, float* __restrict__ part,
    unsigned int* __restrict__ counter, float* __restrict__ out)
{
    const int lane = threadIdx.x & 63;
    const int wid  = threadIdx.x >> 6;

    // XCD-affine swizzle (bijective: NBLK % 8 == 0)
    const int lin   = blockIdx.x;            // 0..1535
    const int xcd   = lin & 7;
    const int slot  = lin >> 3;              // 0..191
    const int strip_local = slot >> 3;       // 0..23
    const int blk   = slot & 7;              // band-block within strip
    const int strip = xcd * STRIPS_PER_XCD + strip_local;   // 0..191
    const int img   = strip / NW;
    const int chunk = strip - img * NW;      // 0..2
    const int band  = blk * WPB + wid;       // 0..31

    // fold chunk min/max -> C1, C2 (uniform; L2-hot)
    float mn = 1e38f, mx = -1e38f;
    #pragma unroll
    for (int ch = 0; ch < CHUNKS; ++ch) {
        mn = fminf(mn, mmpart[2 * (img * CHUNKS + ch)]);
        mx = fmaxf(mx, mmpart[2 * (img * CHUNKS + ch) + 1]);
    }
    const float dr  = mx - mn;
    const float C1p = 2401.0f * (0.01f * dr) * (0.01f * dr);
    const float C2p = 2401.0f * (0.03f * dr) * (0.03f * dr);
    const f32x2 C1v = {C1p, C1p};
    const f32x2 C2v = {C2p, C2p};
    const f32x2 k49   = {49.0f, 49.0f};
    const f32x2 covn1 = {49.0f / 48.0f, 49.0f / 48.0f};
    const f32x2 covn2 = {2.0f * 49.0f / 48.0f, 2.0f * 49.0f / 48.0f};

    // chunk geometry
    const int cbase  = (chunk == 0) ? 0 : (chunk == 1) ? 248 : 496;
    const int out_lo = (chunk == 0) ? 0 : (chunk == 1) ? 250 : 498;
    const int out_hi = (chunk == 0) ? 249 : (chunk == 1) ? 497 : 505;

    const int col0  = cbase + 4 * lane;             // logical first col
    const int col0c = (col0 < 508) ? col0 : 508;    // clamped, 16B aligned
    f32x2 vm01, vm23;
    {
        float v[4];
        #pragma unroll
        for (int j = 0; j < 4; ++j) {
            int oc = col0 + j;
            v[j] = (oc >= out_lo && oc <= out_hi) ? 1.0f : 0.0f;
        }
        vm01 = (f32x2){v[0], v[1]};
        vm23 = (f32x2){v[2], v[3]};
    }

    const int oy0 = band * BH;
    const int nvalid = (OH - oy0) < BH ? (OH - oy0) : BH;   // 16, or 10 (band 31)

    const float* px = X + (size_t)img * NPIX + col0c;
    const float* py = Y + (size_t)img * NPIX + col0c;

    // packed running vertical sums: [0]=cols 0,1  [1]=cols 2,3
    f32x2 Vx[2]  = {{0,0},{0,0}}, Vy[2]  = {{0,0},{0,0}};
    f32x2 Vxy[2] = {{0,0},{0,0}}, Vss[2] = {{0,0},{0,0}};

    #define VADD(xa, ya)                                                     \
    {                                                                        \
        f32x2 xl = (xa).lo, xh = (xa).hi, yl = (ya).lo, yh = (ya).hi;        \
        Vx[0] += xl; Vx[1] += xh; Vy[0] += yl; Vy[1] += yh;                  \
        Vxy[0] += xl * yl; Vxy[1] += xh * yh;                                \
        Vss[0] += xl * xl + yl * yl; Vss[1] += xh * xh + yh * yh;            \
    }
    #define VSUB(xa, ya)                                                     \
    {                                                                        \
        f32x2 xl = (xa).lo, xh = (xa).hi, yl = (ya).lo, yh = (ya).hi;        \
        Vx[0] -= xl; Vx[1] -= xh; Vy[0] -= yl; Vy[1] -= yh;                  \
        Vxy[0] -= xl * yl; Vxy[1] -= xh * yh;                                \
        Vss[0] -= xl * xl + yl * yl; Vss[1] -= xh * xh + yh * yh;            \
    }

    // prologue: accumulate rows oy0..oy0+5 (max 501, no clamp)
    #pragma unroll
    for (int k = 0; k < 6; ++k) {
        f32x4 xa = *(const f32x4*)(px + (size_t)(oy0 + k) * Wc);
        f32x4 ya = *(const f32x4*)(py + (size_t)(oy0 + k) * Wc);
        VADD(xa, ya)
    }

    f32x2 acc2 = {0.f, 0.f};

    // horizontal 7-window via prefix-shuffles: 4 DS ops per stat
    #define H7(V, W0, W1, W2, W3)                                            \
    {                                                                        \
        float v0 = V[0].x, v1 = V[0].y, v2 = V[1].x, v3 = V[1].y;            \
        float t01 = v0 + v1, u23 = v2 + v3;                                  \
        float P3 = t01 + v2, P4 = t01 + u23;                                 \
        float A3 = __shfl_down(P3, 1, 64);                                   \
        float A4 = __shfl_down(P4, 1, 64);                                   \
        float B1 = __shfl_down(v0, 2, 64);                                   \
        float B2 = __shfl_down(t01, 2, 64);                                  \
        float cc = u23 + A4;                                                 \
        W0 = P4 + A3;                                                        \
        W1 = cc + v1;                                                        \
        W2 = cc + B1;                                                        \
        W3 = (v3 + A4) + B2;                                                 \
    }

    // 49^2-prescaled SSIM for a packed pair of columns
    #define SSIM2(wx, wy, wp, ws, vmv)                                       \
    {                                                                        \
        f32x2 t1  = wx * wy;                                                 \
        f32x2 sq  = wx * wx + wy * wy;                                       \
        f32x2 F1  = t1 + t1 + C1v;                                           \
        f32x2 d1  = k49 * wp - t1;                                           \
        f32x2 F2  = covn2 * d1 + C2v;                                        \
        f32x2 F3  = sq + C1v;                                                \
        f32x2 d2  = k49 * ws - sq;                                           \
        f32x2 F4  = covn1 * d2 + C2v;                                        \
        f32x2 den = F3 * F4;                                                 \
        f32x2 num = F1 * F2;                                                 \
        f32x2 rv  = {__builtin_amdgcn_rcpf(den.x),                           \
                     __builtin_amdgcn_rcpf(den.y)};                          \
        acc2 += num * rv * vmv;                                              \
    }

    // running row pointers (strength-reduced addresses)
    const float* pxi = px + (size_t)(oy0 + 6) * Wc;
    const float* pyi = py + (size_t)(oy0 + 6) * Wc;
    const float* pxo = px + (size_t)oy0 * Wc;
    const float* pyo = py + (size_t)oy0 * Wc;

    #pragma unroll 4
    for (int tt = 0; tt < nvalid; ++tt) {
        f32x4 xi = *(const f32x4*)pxi; pxi += Wc;
        f32x4 yi = *(const f32x4*)pyi; pyi += Wc;
        VADD(xi, yi)
        float Wx0, Wx1, Wx2, Wx3;  H7(Vx,  Wx0, Wx1, Wx2, Wx3)
        float Wy0, Wy1, Wy2, Wy3;  H7(Vy,  Wy0, Wy1, Wy2, Wy3)
        float Wp0, Wp1, Wp2, Wp3;  H7(Vxy, Wp0, Wp1, Wp2, Wp3)
        float Ws0, Ws1, Ws2, Ws3;  H7(Vss, Ws0, Ws1, Ws2, Ws3)
        f32x2 wx01 = {Wx0, Wx1}, wx23 = {Wx2, Wx3};
        f32x2 wy01 = {Wy0, Wy1}, wy23 = {Wy2, Wy3};
        f32x2 wp01 = {Wp0, Wp1}, wp23 = {Wp2, Wp3};
        f32x2 ws01 = {Ws0, Ws1}, ws23 = {Ws2, Ws3};
        SSIM2(wx01, wy01, wp01, ws01, vm01)
        SSIM2(wx23, wy23, wp23, ws23, vm23)
        f32x4 xo = *(const f32x4*)pxo; pxo += Wc;
        f32x4 yo = *(const f32x4*)pyo; pyo += Wc;
        VSUB(xo, yo)
    }

    #undef SSIM2
    #undef H7
    #undef VADD
    #undef VSUB

    float acc = acc2.x + acc2.y;
    // deterministic wave reduce + cross-wave LDS fold (one partial per block)
    #pragma unroll
    for (int off = 1; off < 64; off <<= 1)
        acc += __shfl_xor(acc, off, 64);
    __shared__ float sacc[4];
    if (lane == 0) sacc[wid] = acc;
    __syncthreads();

    __shared__ unsigned int s_last;
    if (threadIdx.x == 0) {
        part[lin] = (sacc[0] + sacc[1]) + (sacc[2] + sacc[3]);
        __threadfence();                           // partial visible before count
        unsigned int prev = atomicAdd(counter, 1u);
        s_last = (prev == NBLK - 1) ? 1u : 0u;
    }
    __syncthreads();

    if (s_last) {
        // last-arriving block: deterministic f64 reduction of all partials
        __threadfence();                           // acquire all partials
        __shared__ double sd[256];
        double s = 0.0;
        for (int i = threadIdx.x; i < NPART; i += 256)
            s += (double)part[i];
        sd[threadIdx.x] = s;
        __syncthreads();
        for (int off = 128; off > 0; off >>= 1) {
            if (threadIdx.x < off) sd[threadIdx.x] += sd[threadIdx.x + off];
            __syncthreads();
        }
        if (threadIdx.x == 0)
            out[0] = (float)(sd[0] / ((double)BATCH * OH * OW));
    }
}

extern "C" void kernel_launch(void* const* d_in, const int* in_sizes, int n_in,
                              void* d_out, int out_size, void* d_ws, size_t ws_size,
                              hipStream_t stream) {
    const float* X = (const float*)d_in[0];
    const float* Y = (const float*)d_in[1];
    float* out = (float*)d_out;
    float* ws  = (float*)d_ws;

    float* mmpart = ws;                           // 2*BATCH*CHUNKS = 2048 floats
    float* part   = ws + 2048;                    // NPART = 1536 floats
    unsigned int* counter = (unsigned int*)(ws + 2048 + NPART);

    mm_part_kernel<<<BATCH * CHUNKS, 256, 0, stream>>>(X, Y, mmpart, counter);
    ssim_stream_kernel<<<NBLK, 64 * WPB, 0, stream>>>(X, Y, mmpart, part,
                                                      counter, out);
}

// Round 18
// 75.342 us; speedup vs baseline: 1.6307x; 1.6091x over previous
//
#include <hip/hip_runtime.h>

#define Hc     512
#define Wc     512
#define OH     506
#define OW     506
#define NPIX   (Hc * Wc)
#define BATCH  64
#define CHUNKS 16

#define BH     16                          // output rows per band
#define NBAND  32                          // 31*16=496, band 31 covers 496-505
#define NW     3                           // col-chunks (strips) per image row
#define WPB    4                           // waves (bands) per block
#define BLK_PER_STRIP (NBAND / WPB)        // 8
#define NSTRIP (BATCH * NW)                // 192
#define NBLK   (NSTRIP * BLK_PER_STRIP)    // 1536  (%8==0 -> bijective swizzle)
#define STRIPS_PER_XCD (NSTRIP / 8)        // 24
#define NPART  NBLK

typedef float f32x2 __attribute__((ext_vector_type(2)));
typedef float f32x4 __attribute__((ext_vector_type(4)));

// ---------------- Kernel 1: per-(sample,chunk) min/max partials -------------
__global__ __launch_bounds__(256) void mm_part_kernel(
    const float* __restrict__ X, const float* __restrict__ Y,
    float* __restrict__ part)
{
    int blk = blockIdx.x;            // 0 .. BATCH*CHUNKS-1
    int b   = blk >> 4;
    int ch  = blk & 15;
    size_t base = (size_t)b * NPIX + (size_t)ch * (NPIX / CHUNKS);
    const float4* x4 = (const float4*)(X + base);
    const float4* y4 = (const float4*)(Y + base);
    const int n4 = (NPIX / CHUNKS) / 4;   // 4096

    float mn = 1e38f, mx = -1e38f;
    for (int i = threadIdx.x; i < n4; i += 256) {
        float4 a = x4[i];
        float4 c = y4[i];
        mn = fminf(mn, fminf(fminf(a.x, a.y), fminf(a.z, a.w)));
        mx = fmaxf(mx, fmaxf(fmaxf(a.x, a.y), fmaxf(a.z, a.w)));
        mn = fminf(mn, fminf(fminf(c.x, c.y), fminf(c.z, c.w)));
        mx = fmaxf(mx, fmaxf(fmaxf(c.x, c.y), fmaxf(c.z, c.w)));
    }
    #pragma unroll
    for (int off = 1; off < 64; off <<= 1) {
        mn = fminf(mn, __shfl_xor(mn, off, 64));
        mx = fmaxf(mx, __shfl_xor(mx, off, 64));
    }
    __shared__ float smn[4], smx[4];
    int lane = threadIdx.x & 63, wid = threadIdx.x >> 6;
    if (lane == 0) { smn[wid] = mn; smx[wid] = mx; }
    __syncthreads();
    if (threadIdx.x == 0) {
        mn = fminf(fminf(smn[0], smn[1]), fminf(smn[2], smn[3]));
        mx = fmaxf(fmaxf(smx[0], smx[1]), fmaxf(smx[2], smx[3]));
        part[2 * blk]     = mn;
        part[2 * blk + 1] = mx;
    }
}

// ---------------- Kernel 2: streaming SSIM (champion R13 body) --------------
// XCD-affine block mapping; prefix-shuffle H7 (4 DS/stat); 49^2-prescaled
// SSIM; running row pointers; unroll 4. No LDS staging, no fences, no atomics.
__global__ __launch_bounds__(256, 8) void ssim_stream_kernel(
    const float* __restrict__ X, const float* __restrict__ Y,
    const float* __restrict__ mmpart, float* __restrict__ part)
{
    const int lane = threadIdx.x & 63;
    const int wid  = threadIdx.x >> 6;

    // XCD-affine swizzle (bijective: NBLK % 8 == 0)
    const int lin   = blockIdx.x;            // 0..1535
    const int xcd   = lin & 7;
    const int slot  = lin >> 3;              // 0..191
    const int strip_local = slot >> 3;       // 0..23
    const int blk   = slot & 7;              // band-block within strip
    const int strip = xcd * STRIPS_PER_XCD + strip_local;   // 0..191
    const int img   = strip / NW;
    const int chunk = strip - img * NW;      // 0..2
    const int band  = blk * WPB + wid;       // 0..31

    // fold chunk min/max -> C1, C2 (uniform; L2-hot)
    float mn = 1e38f, mx = -1e38f;
    #pragma unroll
    for (int ch = 0; ch < CHUNKS; ++ch) {
        mn = fminf(mn, mmpart[2 * (img * CHUNKS + ch)]);
        mx = fmaxf(mx, mmpart[2 * (img * CHUNKS + ch) + 1]);
    }
    const float dr  = mx - mn;
    const float C1p = 2401.0f * (0.01f * dr) * (0.01f * dr);
    const float C2p = 2401.0f * (0.03f * dr) * (0.03f * dr);
    const f32x2 C1v = {C1p, C1p};
    const f32x2 C2v = {C2p, C2p};
    const f32x2 k49   = {49.0f, 49.0f};
    const f32x2 covn1 = {49.0f / 48.0f, 49.0f / 48.0f};
    const f32x2 covn2 = {2.0f * 49.0f / 48.0f, 2.0f * 49.0f / 48.0f};

    // chunk geometry
    const int cbase  = (chunk == 0) ? 0 : (chunk == 1) ? 248 : 496;
    const int out_lo = (chunk == 0) ? 0 : (chunk == 1) ? 250 : 498;
    const int out_hi = (chunk == 0) ? 249 : (chunk == 1) ? 497 : 505;

    const int col0  = cbase + 4 * lane;             // logical first col
    const int col0c = (col0 < 508) ? col0 : 508;    // clamped, 16B aligned
    f32x2 vm01, vm23;
    {
        float v[4];
        #pragma unroll
        for (int j = 0; j < 4; ++j) {
            int oc = col0 + j;
            v[j] = (oc >= out_lo && oc <= out_hi) ? 1.0f : 0.0f;
        }
        vm01 = (f32x2){v[0], v[1]};
        vm23 = (f32x2){v[2], v[3]};
    }

    const int oy0 = band * BH;
    const int nvalid = (OH - oy0) < BH ? (OH - oy0) : BH;   // 16, or 10 (band 31)

    const float* px = X + (size_t)img * NPIX + col0c;
    const float* py = Y + (size_t)img * NPIX + col0c;

    // packed running vertical sums: [0]=cols 0,1  [1]=cols 2,3
    f32x2 Vx[2]  = {{0,0},{0,0}}, Vy[2]  = {{0,0},{0,0}};
    f32x2 Vxy[2] = {{0,0},{0,0}}, Vss[2] = {{0,0},{0,0}};

    #define VADD(xa, ya)                                                     \
    {                                                                        \
        f32x2 xl = (xa).lo, xh = (xa).hi, yl = (ya).lo, yh = (ya).hi;        \
        Vx[0] += xl; Vx[1] += xh; Vy[0] += yl; Vy[1] += yh;                  \
        Vxy[0] += xl * yl; Vxy[1] += xh * yh;                                \
        Vss[0] += xl * xl + yl * yl; Vss[1] += xh * xh + yh * yh;            \
    }
    #define VSUB(xa, ya)                                                     \
    {                                                                        \
        f32x2 xl = (xa).lo, xh = (xa).hi, yl = (ya).lo, yh = (ya).hi;        \
        Vx[0] -= xl; Vx[1] -= xh; Vy[0] -= yl; Vy[1] -= yh;                  \
        Vxy[0] -= xl * yl; Vxy[1] -= xh * yh;                                \
        Vss[0] -= xl * xl + yl * yl; Vss[1] -= xh * xh + yh * yh;            \
    }

    // prologue: accumulate rows oy0..oy0+5 (max 501, no clamp)
    #pragma unroll
    for (int k = 0; k < 6; ++k) {
        f32x4 xa = *(const f32x4*)(px + (size_t)(oy0 + k) * Wc);
        f32x4 ya = *(const f32x4*)(py + (size_t)(oy0 + k) * Wc);
        VADD(xa, ya)
    }

    f32x2 acc2 = {0.f, 0.f};

    // horizontal 7-window via prefix-shuffles: 4 DS ops per stat
    #define H7(V, W0, W1, W2, W3)                                            \
    {                                                                        \
        float v0 = V[0].x, v1 = V[0].y, v2 = V[1].x, v3 = V[1].y;            \
        float t01 = v0 + v1, u23 = v2 + v3;                                  \
        float P3 = t01 + v2, P4 = t01 + u23;                                 \
        float A3 = __shfl_down(P3, 1, 64);                                   \
        float A4 = __shfl_down(P4, 1, 64);                                   \
        float B1 = __shfl_down(v0, 2, 64);                                   \
        float B2 = __shfl_down(t01, 2, 64);                                  \
        float cc = u23 + A4;                                                 \
        W0 = P4 + A3;                                                        \
        W1 = cc + v1;                                                        \
        W2 = cc + B1;                                                        \
        W3 = (v3 + A4) + B2;                                                 \
    }

    // 49^2-prescaled SSIM for a packed pair of columns
    #define SSIM2(wx, wy, wp, ws, vmv)                                       \
    {                                                                        \
        f32x2 t1  = wx * wy;                                                 \
        f32x2 sq  = wx * wx + wy * wy;                                       \
        f32x2 F1  = t1 + t1 + C1v;                                           \
        f32x2 d1  = k49 * wp - t1;                                           \
        f32x2 F2  = covn2 * d1 + C2v;                                        \
        f32x2 F3  = sq + C1v;                                                \
        f32x2 d2  = k49 * ws - sq;                                           \
        f32x2 F4  = covn1 * d2 + C2v;                                        \
        f32x2 den = F3 * F4;                                                 \
        f32x2 num = F1 * F2;                                                 \
        f32x2 rv  = {__builtin_amdgcn_rcpf(den.x),                           \
                     __builtin_amdgcn_rcpf(den.y)};                          \
        acc2 += num * rv * vmv;                                              \
    }

    // running row pointers (strength-reduced addresses)
    const float* pxi = px + (size_t)(oy0 + 6) * Wc;
    const float* pyi = py + (size_t)(oy0 + 6) * Wc;
    const float* pxo = px + (size_t)oy0 * Wc;
    const float* pyo = py + (size_t)oy0 * Wc;

    #pragma unroll 4
    for (int tt = 0; tt < nvalid; ++tt) {
        f32x4 xi = *(const f32x4*)pxi; pxi += Wc;
        f32x4 yi = *(const f32x4*)pyi; pyi += Wc;
        VADD(xi, yi)
        float Wx0, Wx1, Wx2, Wx3;  H7(Vx,  Wx0, Wx1, Wx2, Wx3)
        float Wy0, Wy1, Wy2, Wy3;  H7(Vy,  Wy0, Wy1, Wy2, Wy3)
        float Wp0, Wp1, Wp2, Wp3;  H7(Vxy, Wp0, Wp1, Wp2, Wp3)
        float Ws0, Ws1, Ws2, Ws3;  H7(Vss, Ws0, Ws1, Ws2, Ws3)
        f32x2 wx01 = {Wx0, Wx1}, wx23 = {Wx2, Wx3};
        f32x2 wy01 = {Wy0, Wy1}, wy23 = {Wy2, Wy3};
        f32x2 wp01 = {Wp0, Wp1}, wp23 = {Wp2, Wp3};
        f32x2 ws01 = {Ws0, Ws1}, ws23 = {Ws2, Ws3};
        SSIM2(wx01, wy01, wp01, ws01, vm01)
        SSIM2(wx23, wy23, wp23, ws23, vm23)
        f32x4 xo = *(const f32x4*)pxo; pxo += Wc;
        f32x4 yo = *(const f32x4*)pyo; pyo += Wc;
        VSUB(xo, yo)
    }

    #undef SSIM2
    #undef H7
    #undef VADD
    #undef VSUB

    float acc = acc2.x + acc2.y;
    // deterministic wave reduce + cross-wave LDS fold (one partial per block)
    #pragma unroll
    for (int off = 1; off < 64; off <<= 1)
        acc += __shfl_xor(acc, off, 64);
    __shared__ float sacc[4];
    if (lane == 0) sacc[wid] = acc;
    __syncthreads();
    if (threadIdx.x == 0)
        part[lin] = (sacc[0] + sacc[1]) + (sacc[2] + sacc[3]);
}

// ---------------- Kernel 3: final deterministic f64 reduction ---------------
__global__ __launch_bounds__(1024) void final_reduce_kernel(
    const float* __restrict__ part, float* __restrict__ out)
{
    __shared__ double sd[1024];
    double s = 0.0;
    for (int i = threadIdx.x; i < NPART; i += 1024)
        s += (double)part[i];
    sd[threadIdx.x] = s;
    __syncthreads();
    for (int off = 512; off > 0; off >>= 1) {
        if (threadIdx.x < off) sd[threadIdx.x] += sd[threadIdx.x + off];
        __syncthreads();
    }
    if (threadIdx.x == 0)
        out[0] = (float)(sd[0] / ((double)BATCH * OH * OW));
}

extern "C" void kernel_launch(void* const* d_in, const int* in_sizes, int n_in,
                              void* d_out, int out_size, void* d_ws, size_t ws_size,
                              hipStream_t stream) {
    const float* X = (const float*)d_in[0];
    const float* Y = (const float*)d_in[1];
    float* out = (float*)d_out;
    float* ws  = (float*)d_ws;

    float* mmpart = ws;                   // 2 * BATCH * CHUNKS = 2048 floats
    float* part   = ws + 2048;            // NPART = 1536 floats

    mm_part_kernel<<<BATCH * CHUNKS, 256, 0, stream>>>(X, Y, mmpart);
    ssim_stream_kernel<<<NBLK, 64 * WPB, 0, stream>>>(X, Y, mmpart, part);
    final_reduce_kernel<<<1, 1024, 0, stream>>>(part, out);
}